// Round 1
// baseline (368.088 us; speedup 1.0000x reference)
//
#include <hip/hip_runtime.h>

#define LO 506      // L_out
#define LL 512      // L
#define CC 128      // C
#define FF 128      // F
#define KC 896      // K*C (reduction dim)
#define BK 64       // K-tile
#define NK 14       // 896/64
#define XS 72       // Xs row stride in bf16 elems (64 + 8 pad; 144 B row: 16B-aligned, phase-balanced banks)

typedef __attribute__((ext_vector_type(8))) short short8;     // 8 bf16 = 4 VGPR (MFMA operand)
typedef __attribute__((ext_vector_type(4))) float floatx4;    // MFMA acc / float4 load
typedef __attribute__((ext_vector_type(4))) unsigned int uintx4;
typedef unsigned short ushort_t;

static __device__ __forceinline__ ushort_t f2bf(float f) {    // RNE f32 -> bf16
    union { float f; unsigned int u; } c; c.f = f;
    unsigned int u = c.u;
    return (ushort_t)((u + 0x7fffu + ((u >> 16) & 1u)) >> 16);
}
static __device__ __forceinline__ unsigned int pk2(float a, float b) {
    return (unsigned int)f2bf(a) | ((unsigned int)f2bf(b) << 16);
}

// grid = 506: one block per output position l. 512 threads = 8 waves.
// Each block computes the FULL 128-batch x 128-f tile for its l, so
// W[l] (896x128 fp32 = 458 KB) is streamed from HBM exactly once —
// no reliance on cross-XCD L2/L3 dedupe between sibling half-blocks.
// 2 blocks/CU (16 waves/CU), VGPR cap 128 with live set ~110 (no spill).
__global__ __launch_bounds__(512, 4)
void local_block_kernel(const float* __restrict__ x,
                        const float* __restrict__ wg,
                        const float* __restrict__ bias,
                        const float* __restrict__ gamma,
                        const float* __restrict__ beta,
                        const float* __restrict__ mmean,
                        const float* __restrict__ mvar,
                        float* __restrict__ out)
{
    const int l    = blockIdx.x;          // output position, owns W[l] (896x128 fp32)
    const int t    = threadIdx.x;         // 512 threads = 8 waves
    const int lane = t & 63;
    const int wave = t >> 6;              // 0..7
    const int q    = lane >> 4;           // quad within wave
    const int l16  = lane & 15;
    const int wr   = wave >> 1;           // wave row: which batch 32-block (0..3)
    const int wc   = wave & 1;            // wave col: f 64-half

    __shared__ __align__(16) ushort_t Xs[128 * XS];   // [b][k] bf16, k-contig (18.4 KB)
    __shared__ __align__(16) ushort_t Wt[128 * 64];   // [f][k] bf16, k-contig, 16B-unit XOR swizzle (16 KB)

    // ---- A staging map: thread -> (row am = t>>2 in 0..127, k-quarter = (t&3)*16); 16 floats = 4 x float4
    const int am  = t >> 2;
    const int ak0 = (t & 3) * 16;
    const float* aptr = x + (size_t)am * (LL * CC) + l * CC + ak0;
    ushort_t* asd = &Xs[am * XS + ak0];

    // ---- W staging map: thread -> (f = t&127, k 16-row group = (t>>7)*16); 16 strided dword loads
    const int wf  = t & 127;
    const int wkh = (t >> 7) * 16;        // 0,16,32,48
    const float* wptr = wg + (size_t)l * (KC * FF) + wf;

    floatx4 acc[2][4] = {};               // 32 fp32 accumulators (2 m-tiles x 4 n-tiles)

    floatx4 areg[4];
    float   wreg[16];

#define LOAD_A(KT) { const float* p = aptr + (KT) * BK;                         \
        _Pragma("unroll") for (int v = 0; v < 4; ++v)                           \
            areg[v] = *(const floatx4*)(p + v * 4); }

#define LOAD_W(KT) { const float* p = wptr + (size_t)((KT) * BK + wkh) * FF;    \
        _Pragma("unroll") for (int j = 0; j < 16; ++j)                          \
            wreg[j] = p[j * FF]; }

    LOAD_A(0); LOAD_W(0);

    for (int kt = 0; kt < NK; ++kt) {
        __syncthreads();                  // previous tile's LDS reads done
        // ---- stage A: convert 16 f32 -> 16 bf16, 2 x ds_write_b128
#pragma unroll
        for (int v = 0; v < 2; ++v) {
            uintx4 av = { pk2(areg[2*v].x,   areg[2*v].y),
                          pk2(areg[2*v].z,   areg[2*v].w),
                          pk2(areg[2*v+1].x, areg[2*v+1].y),
                          pk2(areg[2*v+1].z, areg[2*v+1].w) };
            *(uintx4*)(asd + v * 8) = av;
        }
        // ---- stage W transposed: 8 k-contig bf16 per f per b128, XOR swizzle on 16B units
#pragma unroll
        for (int rr = 0; rr < 2; ++rr) {
            uintx4 wv = { pk2(wreg[rr*8+0], wreg[rr*8+1]),
                          pk2(wreg[rr*8+2], wreg[rr*8+3]),
                          pk2(wreg[rr*8+4], wreg[rr*8+5]),
                          pk2(wreg[rr*8+6], wreg[rr*8+7]) };
            int unit = ((wkh >> 3) + rr) ^ (wf & 7);          // k-unit XOR f
            *(uintx4*)&Wt[wf * 64 + unit * 8] = wv;
        }
        __syncthreads();
        if (kt + 1 < NK) { LOAD_A(kt + 1); LOAD_W(kt + 1); }  // register prefetch overlaps MFMA
        // ---- compute: 2 x 8 MFMAs (K=32 each)
#pragma unroll
        for (int r = 0; r < 2; ++r) {
            short8 af[2], bfr[4];
#pragma unroll
            for (int mi = 0; mi < 2; ++mi)
                af[mi] = *(const short8*)&Xs[(wr*32 + mi*16 + l16) * XS + r*32 + q*8];
#pragma unroll
            for (int ni = 0; ni < 4; ++ni) {
                int f = wc*64 + ni*16 + l16;
                int unit = (r*4 + q) ^ (f & 7);
                bfr[ni] = *(const short8*)&Wt[f * 64 + unit * 8];
            }
#pragma unroll
            for (int mi = 0; mi < 2; ++mi)
#pragma unroll
                for (int ni = 0; ni < 4; ++ni)
                    acc[mi][ni] = __builtin_amdgcn_mfma_f32_16x16x32_bf16(
                        af[mi], bfr[ni], acc[mi][ni], 0, 0, 0);
        }
    }

    // ---- epilogue: fold bias + BN into per-f scale/offset, relu, store fp32
#pragma unroll
    for (int ni = 0; ni < 4; ++ni) {
        int f = wc*64 + ni*16 + l16;
        float inv = gamma[f] * rsqrtf(mvar[f] + 1e-3f);
        float off = bias[l * FF + f] * inv + beta[f] - mmean[f] * inv;
#pragma unroll
        for (int mi = 0; mi < 2; ++mi) {
#pragma unroll
            for (int rg = 0; rg < 4; ++rg) {
                int b = wr*32 + mi*16 + q*4 + rg;   // C/D: row=(lane>>4)*4+reg
                float v = acc[mi][ni][rg] * inv + off;
                out[((size_t)b * LO + l) * FF + f] = fmaxf(v, 0.0f);
            }
        }
    }
#undef LOAD_A
#undef LOAD_W
}

extern "C" void kernel_launch(void* const* d_in, const int* in_sizes, int n_in,
                              void* d_out, int out_size, void* d_ws, size_t ws_size,
                              hipStream_t stream) {
    const float* x     = (const float*)d_in[0];
    const float* w     = (const float*)d_in[1];
    const float* bias  = (const float*)d_in[2];
    const float* gamma = (const float*)d_in[3];
    const float* beta  = (const float*)d_in[4];
    const float* mmean = (const float*)d_in[5];
    const float* mvar  = (const float*)d_in[6];
    float* out = (float*)d_out;

    local_block_kernel<<<dim3(LO), dim3(512), 0, stream>>>(
        x, w, bias, gamma, beta, mmean, mvar, out);
}

// Round 2
// 361.129 us; speedup vs baseline: 1.0193x; 1.0193x over previous
//
#include <hip/hip_runtime.h>

#define LO 506      // L_out
#define LL 512      // L
#define CC 128      // C
#define FF 128      // F
#define KC 896      // K*C (reduction dim)
#define BK 32       // K-tile (shrunk from 64: halves prefetch+fragment registers -> no spill risk)
#define NK 28       // 896/32
#define XS 40       // Xs row stride in bf16 (32 + 8 pad; 80 B rows: 16B-aligned b128, 2-way banks = free)
#define WS 40       // Wt row stride in bf16 (same geometry; replaces XOR swizzle)

typedef __attribute__((ext_vector_type(8))) short short8;     // 8 bf16 = 4 VGPR (MFMA operand)
typedef __attribute__((ext_vector_type(4))) float floatx4;    // MFMA acc / float4 load
typedef __attribute__((ext_vector_type(4))) unsigned int uintx4;
typedef unsigned short ushort_t;

static __device__ __forceinline__ ushort_t f2bf(float f) {    // RNE f32 -> bf16
    union { float f; unsigned int u; } c; c.f = f;
    unsigned int u = c.u;
    return (ushort_t)((u + 0x7fffu + ((u >> 16) & 1u)) >> 16);
}
static __device__ __forceinline__ unsigned int pk2(float a, float b) {
    return (unsigned int)f2bf(a) | ((unsigned int)f2bf(b) << 16);
}

// grid = 506: one block per output position l; 512 threads = 8 waves; full 128b x 128f tile.
// W[l] (896x128 fp32, 458 KB) is streamed from HBM exactly once by construction.
// BK=32 keeps per-thread live registers ~90 << 128 cap (launch_bounds 512,4 -> 2 blocks/CU):
//   acc 32 + areg 8 + wreg 8 + af 8 + bfr 16 + addressing ~10.
// W loads and out stores are nontemporal: both are single-use, keep L2/L3 for the 7x-reused x.
__global__ __launch_bounds__(512, 4)
void local_block_kernel(const float* __restrict__ x,
                        const float* __restrict__ wg,
                        const float* __restrict__ bias,
                        const float* __restrict__ gamma,
                        const float* __restrict__ beta,
                        const float* __restrict__ mmean,
                        const float* __restrict__ mvar,
                        float* __restrict__ out)
{
    const int l    = blockIdx.x;          // output position, owns W[l]
    const int t    = threadIdx.x;         // 512 threads = 8 waves
    const int lane = t & 63;
    const int wave = t >> 6;              // 0..7
    const int q    = lane >> 4;           // quad within wave (k-group)
    const int l16  = lane & 15;
    const int wr   = wave >> 1;           // wave row: batch 32-block (0..3)
    const int wc   = wave & 1;            // wave col: f 64-half

    __shared__ __align__(16) ushort_t Xs[128 * XS];   // [b][k] bf16 (10.0 KB)
    __shared__ __align__(16) ushort_t Wt[128 * WS];   // [f][k] bf16 (10.0 KB)

    // ---- A staging map: thread -> (row = t>>2 in 0..127, k-chunk = (t&3)*8); 8 floats = 2 float4
    const int am  = t >> 2;
    const int ak0 = (t & 3) * 8;
    const float* aptr = x + (size_t)am * (LL * CC) + l * CC + ak0;
    ushort_t* asd = &Xs[am * XS + ak0];

    // ---- W staging map: thread -> (f = t&127, k 8-group = (t>>7)*8); 8 strided dword loads
    const int wf  = t & 127;
    const int wk  = (t >> 7) * 8;         // 0,8,16,24
    const float* wptr = wg + (size_t)l * (KC * FF) + wf;
    ushort_t* wsd = &Wt[wf * WS + wk];

    floatx4 acc[2][4] = {};               // 32 fp32 accumulators (2 m-tiles x 4 n-tiles)

    floatx4 areg[2];                      // 8 floats prefetch (A)
    float   wreg[8];                      // 8 floats prefetch (W)

#define LOAD_A(KT) { const float* p = aptr + (KT) * BK;                         \
        areg[0] = *(const floatx4*)(p);                                         \
        areg[1] = *(const floatx4*)(p + 4); }

#define LOAD_W(KT) { const float* p = wptr + (size_t)((KT) * BK + wk) * FF;     \
        _Pragma("unroll") for (int j = 0; j < 8; ++j)                           \
            wreg[j] = __builtin_nontemporal_load(p + j * FF); }

    LOAD_A(0); LOAD_W(0);

    for (int kt = 0; kt < NK; ++kt) {
        __syncthreads();                  // previous tile's LDS reads done
        // ---- stage A: 8 f32 -> 8 bf16, one ds_write_b128
        {
            uintx4 av = { pk2(areg[0].x, areg[0].y),
                          pk2(areg[0].z, areg[0].w),
                          pk2(areg[1].x, areg[1].y),
                          pk2(areg[1].z, areg[1].w) };
            *(uintx4*)asd = av;
        }
        // ---- stage W transposed: 8 k-contig bf16 for one f, one ds_write_b128
        {
            uintx4 wv = { pk2(wreg[0], wreg[1]),
                          pk2(wreg[2], wreg[3]),
                          pk2(wreg[4], wreg[5]),
                          pk2(wreg[6], wreg[7]) };
            *(uintx4*)wsd = wv;
        }
        __syncthreads();
        if (kt + 1 < NK) { LOAD_A(kt + 1); LOAD_W(kt + 1); }  // register prefetch overlaps MFMA
        // ---- compute: 8 MFMAs (one K=32 step)
        short8 af[2], bfr[4];
#pragma unroll
        for (int mi = 0; mi < 2; ++mi)
            af[mi] = *(const short8*)&Xs[(wr*32 + mi*16 + l16) * XS + q*8];
#pragma unroll
        for (int ni = 0; ni < 4; ++ni)
            bfr[ni] = *(const short8*)&Wt[(wc*64 + ni*16 + l16) * WS + q*8];
#pragma unroll
        for (int mi = 0; mi < 2; ++mi)
#pragma unroll
            for (int ni = 0; ni < 4; ++ni)
                acc[mi][ni] = __builtin_amdgcn_mfma_f32_16x16x32_bf16(
                    af[mi], bfr[ni], acc[mi][ni], 0, 0, 0);
    }

    // ---- epilogue: fold bias + BN into per-f scale/offset, relu, nontemporal store fp32
#pragma unroll
    for (int ni = 0; ni < 4; ++ni) {
        int f = wc*64 + ni*16 + l16;
        float inv = gamma[f] * rsqrtf(mvar[f] + 1e-3f);
        float off = bias[l * FF + f] * inv + beta[f] - mmean[f] * inv;
#pragma unroll
        for (int mi = 0; mi < 2; ++mi) {
#pragma unroll
            for (int rg = 0; rg < 4; ++rg) {
                int b = wr*32 + mi*16 + q*4 + rg;   // C/D: row=(lane>>4)*4+reg
                float v = acc[mi][ni][rg] * inv + off;
                __builtin_nontemporal_store(fmaxf(v, 0.0f),
                    &out[((size_t)b * LO + l) * FF + f]);
            }
        }
    }
#undef LOAD_A
#undef LOAD_W
}

extern "C" void kernel_launch(void* const* d_in, const int* in_sizes, int n_in,
                              void* d_out, int out_size, void* d_ws, size_t ws_size,
                              hipStream_t stream) {
    const float* x     = (const float*)d_in[0];
    const float* w     = (const float*)d_in[1];
    const float* bias  = (const float*)d_in[2];
    const float* gamma = (const float*)d_in[3];
    const float* beta  = (const float*)d_in[4];
    const float* mmean = (const float*)d_in[5];
    const float* mvar  = (const float*)d_in[6];
    float* out = (float*)d_out;

    local_block_kernel<<<dim3(LO), dim3(512), 0, stream>>>(
        x, w, bias, gamma, beta, mmean, mvar, out);
}

// Round 3
// 347.153 us; speedup vs baseline: 1.0603x; 1.0403x over previous
//
#include <hip/hip_runtime.h>

#define LO 506      // L_out
#define LL 512      // L
#define CC 128      // C
#define FF 128      // F
#define KC 896      // K*C (reduction dim)
#define BK 32       // K-tile
#define NK 28       // 896/32
#define XS 40       // Xs row stride in bf16 (32 + 8 pad; 80 B rows: 16B-aligned b128, 2-way banks = free)
#define WS 40       // Wt row stride in bf16

typedef __attribute__((ext_vector_type(8))) short short8;     // 8 bf16 = 4 VGPR (MFMA operand)
typedef __attribute__((ext_vector_type(4))) float floatx4;    // MFMA acc / float4 load
typedef __attribute__((ext_vector_type(4))) unsigned int uintx4;
typedef unsigned short ushort_t;

static __device__ __forceinline__ ushort_t f2bf(float f) {    // RNE f32 -> bf16
    union { float f; unsigned int u; } c; c.f = f;
    unsigned int u = c.u;
    return (ushort_t)((u + 0x7fffu + ((u >> 16) & 1u)) >> 16);
}
static __device__ __forceinline__ unsigned int pk2(float a, float b) {
    return (unsigned int)f2bf(a) | ((unsigned int)f2bf(b) << 16);
}

// grid = 506, one block per l, 512 threads = 8 waves, full 128b x 128f tile.
// This round:
//  - bijective XCD-chunk swizzle: the 64 co-resident blocks per XCD cover a
//    contiguous l-range -> their shared x rows (~4.2 MB window) live in that
//    XCD's L2. W is nontemporal (single-use) so it doesn't evict x.
//  - LDS double-buffer (40 KB): ONE barrier per K-tile.
//  - 2-deep register prefetch + raw s_barrier with lgkmcnt(0) only: global
//    loads stay in flight ACROSS barriers (no vmcnt(0) drain per tile).
__global__ __launch_bounds__(512, 4)
void local_block_kernel(const float* __restrict__ x,
                        const float* __restrict__ wg,
                        const float* __restrict__ bias,
                        const float* __restrict__ gamma,
                        const float* __restrict__ beta,
                        const float* __restrict__ mmean,
                        const float* __restrict__ mvar,
                        float* __restrict__ out)
{
    // ---- bijective XCD-chunk swizzle (nwg=506, 8 XCDs: chunks 64,64,63x6)
    const int bid = blockIdx.x;
    const int xcd = bid & 7;
    const int idx = bid >> 3;
    const int q8  = LO >> 3;              // 63
    const int r8  = LO & 7;               // 2
    const int l   = (xcd < r8) ? xcd * (q8 + 1) + idx
                               : r8 * (q8 + 1) + (xcd - r8) * q8 + idx;

    const int t    = threadIdx.x;         // 512 threads = 8 waves
    const int lane = t & 63;
    const int wave = t >> 6;              // 0..7
    const int q    = lane >> 4;           // quad within wave (k-group)
    const int l16  = lane & 15;
    const int wr   = wave >> 1;           // wave row: batch 32-block (0..3)
    const int wc   = wave & 1;            // wave col: f 64-half

    __shared__ __align__(16) ushort_t Xs[2][128 * XS];   // 2 x 10 KB
    __shared__ __align__(16) ushort_t Wt[2][128 * WS];   // 2 x 10 KB  (40 KB total)

    // ---- A staging map: thread -> (row = t>>2, k-chunk = (t&3)*8); 8 floats = 2 float4
    const int am  = t >> 2;
    const int ak0 = (t & 3) * 8;
    const float* aptr = x + (size_t)am * (LL * CC) + l * CC + ak0;

    // ---- W staging map: thread -> (f = t&127, k 8-group = (t>>7)*8); 8 strided dword loads
    const int wf  = t & 127;
    const int wk  = (t >> 7) * 8;         // 0,8,16,24
    const float* wptr = wg + (size_t)l * (KC * FF) + wf;

    floatx4 acc[2][4] = {};               // 32 fp32 accumulators

    floatx4 areg0[2], areg1[2];           // 2-deep A prefetch (8+8 VGPR)
    float   wreg0[8], wreg1[8];           // 2-deep W prefetch (8+8 VGPR)

#define LOAD_A(AR, KT) { const float* p = aptr + (KT) * BK;                     \
        AR[0] = *(const floatx4*)(p);                                           \
        AR[1] = *(const floatx4*)(p + 4); }

#define LOAD_W(WR, KT) { const float* p = wptr + (size_t)((KT) * BK + wk) * FF; \
        _Pragma("unroll") for (int j = 0; j < 8; ++j)                           \
            WR[j] = __builtin_nontemporal_load(p + j * FF); }

#define STAGE(S, AR, WR) {                                                      \
        uintx4 av = { pk2(AR[0].x, AR[0].y), pk2(AR[0].z, AR[0].w),             \
                      pk2(AR[1].x, AR[1].y), pk2(AR[1].z, AR[1].w) };           \
        *(uintx4*)&Xs[S][am * XS + ak0] = av;                                   \
        uintx4 wv = { pk2(WR[0], WR[1]), pk2(WR[2], WR[3]),                     \
                      pk2(WR[4], WR[5]), pk2(WR[6], WR[7]) };                   \
        *(uintx4*)&Wt[S][wf * WS + wk] = wv; }

    // Barrier with LDS-only drain: own ds_writes complete (lgkmcnt), then
    // s_barrier; memory-clobber asms fence LDS ops on both sides so no
    // ds_read/ds_write crosses. vmcnt untouched -> prefetch stays in flight.
#define BAR() {                                                                 \
        asm volatile("s_waitcnt lgkmcnt(0)" ::: "memory");                      \
        __builtin_amdgcn_s_barrier();                                           \
        asm volatile("" ::: "memory"); }

#define COMPUTE(S) {                                                            \
        short8 af[2], bfr[4];                                                   \
        _Pragma("unroll") for (int mi = 0; mi < 2; ++mi)                        \
            af[mi] = *(const short8*)&Xs[S][(wr*32 + mi*16 + l16) * XS + q*8];  \
        _Pragma("unroll") for (int ni = 0; ni < 4; ++ni)                        \
            bfr[ni] = *(const short8*)&Wt[S][(wc*64 + ni*16 + l16) * WS + q*8]; \
        _Pragma("unroll") for (int mi = 0; mi < 2; ++mi)                        \
            _Pragma("unroll") for (int ni = 0; ni < 4; ++ni)                    \
                acc[mi][ni] = __builtin_amdgcn_mfma_f32_16x16x32_bf16(          \
                    af[mi], bfr[ni], acc[mi][ni], 0, 0, 0); }

    LOAD_A(areg0, 0); LOAD_W(wreg0, 0);
    LOAD_A(areg1, 1); LOAD_W(wreg1, 1);

    for (int kt = 0; kt < NK; kt += 2) {
        // ---- tile kt -> LDS buffer 0
        STAGE(0, areg0, wreg0);
        if (kt + 2 < NK) { LOAD_A(areg0, kt + 2); LOAD_W(wreg0, kt + 2); }
        BAR();
        COMPUTE(0);
        // ---- tile kt+1 -> LDS buffer 1 (safe: other waves still reading buf0 only)
        STAGE(1, areg1, wreg1);
        if (kt + 3 < NK) { LOAD_A(areg1, kt + 3); LOAD_W(wreg1, kt + 3); }
        BAR();
        COMPUTE(1);
    }

    // ---- epilogue: fold bias + BN into per-f scale/offset, relu, nontemporal store
#pragma unroll
    for (int ni = 0; ni < 4; ++ni) {
        int f = wc*64 + ni*16 + l16;
        float inv = gamma[f] * rsqrtf(mvar[f] + 1e-3f);
        float off = bias[l * FF + f] * inv + beta[f] - mmean[f] * inv;
#pragma unroll
        for (int mi = 0; mi < 2; ++mi) {
#pragma unroll
            for (int rg = 0; rg < 4; ++rg) {
                int b = wr*32 + mi*16 + q*4 + rg;   // C/D: row=(lane>>4)*4+reg
                float v = acc[mi][ni][rg] * inv + off;
                __builtin_nontemporal_store(fmaxf(v, 0.0f),
                    &out[((size_t)b * LO + l) * FF + f]);
            }
        }
    }
#undef LOAD_A
#undef LOAD_W
#undef STAGE
#undef BAR
#undef COMPUTE
}

extern "C" void kernel_launch(void* const* d_in, const int* in_sizes, int n_in,
                              void* d_out, int out_size, void* d_ws, size_t ws_size,
                              hipStream_t stream) {
    const float* x     = (const float*)d_in[0];
    const float* w     = (const float*)d_in[1];
    const float* bias  = (const float*)d_in[2];
    const float* gamma = (const float*)d_in[3];
    const float* beta  = (const float*)d_in[4];
    const float* mmean = (const float*)d_in[5];
    const float* mvar  = (const float*)d_in[6];
    float* out = (float*)d_out;

    local_block_kernel<<<dim3(LO), dim3(512), 0, stream>>>(
        x, w, bias, gamma, beta, mmean, mvar, out);
}